// Round 1
// baseline (699.870 us; speedup 1.0000x reference)
//
#include <hip/hip_runtime.h>
#include <math.h>

#define T 8
#define NI 20000
#define NK 50000
#define F 128
#define H 256
#define O 128
#define E 500000
#define G3 (3*H)          // 768
#define MAXS 256          // slot cap per timestep (E[slots]=25)
#define CAP1 256          // per-slot e1 edge cap (E[edges/slot]=10)
#define BMW 1568          // ceil(NK/32)
#define NB 8              // persistent GRU blocks
#define RPB 32            // h-indices per GRU block (H/NB)
#define EQ (E/4)          // int4 quads per timestep

// ---------------- workspace layout (bytes) ----------------
// zeroed prefix:
#define OFF_CNT2   0                        // T ints
#define OFF_ITEMS  32                       // T*MAXS ints
#define OFF_CNT1   (32 + T*MAXS*4)          // T*MAXS ints
#define OFF_HSUM   (OFF_CNT1 + T*MAXS*4)    // T*H floats
#define OFF_BAR    (OFF_HSUM + T*H*4)       // 16 ints
#define OFF_GBM    (OFF_BAR + 64)           // T*BMW uints
#define WS_ZERO    (OFF_GBM + T*BMW*4)      // ~73 KB memset
// not zeroed (fully written before read):
#define OFF_LIST1  WS_ZERO                  // T*MAXS*CAP1 ints (2 MB)
#define OFF_GI     (OFF_LIST1 + (size_t)T*MAXS*CAP1*4)  // T*G3 floats
#define OFF_RNN    (OFF_GI + T*G3*4)        // T*H floats
#define WS_USED    (OFF_RNN + T*H*4)

// K1: scan e2_dst (int4) for edges into target; record src items (slots),
// set global item bitmap. No feature reads/atomics here anymore.
__global__ void k_find_e2(const int* __restrict__ e2_src, const int* __restrict__ e2_dst,
                          const int* __restrict__ target_p,
                          int* __restrict__ cnt2, int* __restrict__ items,
                          unsigned* __restrict__ gbm) {
    int t = blockIdx.y;
    long q = (long)blockIdx.x * 256 + threadIdx.x;
    if (q >= EQ) return;
    int target = *target_p;
    const int4 d4 = ((const int4*)(e2_dst + (long)t * E))[q];
    int dd[4] = {d4.x, d4.y, d4.z, d4.w};
#pragma unroll
    for (int c = 0; c < 4; ++c) {
        if (dd[c] == target) {
            long j = q * 4 + c;
            int src = e2_src[(long)t * E + j];
            int pos = atomicAdd(&cnt2[t], 1);
            if (pos < MAXS) {
                items[t * MAXS + pos] = src;
                atomicOr(&gbm[t * BMW + (src >> 5)], 1u << (src & 31));
            }
        }
    }
}

// K2: scan e1_dst (int4) against global bitmap; matching edges append their
// src index into the slot's list. No LDS build, no feature atomics.
__global__ void k_scan_e1(const int* __restrict__ e1_src, const int* __restrict__ e1_dst,
                          const int* __restrict__ cnt2, const int* __restrict__ items,
                          const unsigned* __restrict__ gbm,
                          int* __restrict__ cnt1, int* __restrict__ list1) {
    int t = blockIdx.y;
    long q = (long)blockIdx.x * 256 + threadIdx.x;
    if (q >= EQ) return;
    const unsigned* bm = gbm + t * BMW;
    const int4 d4 = ((const int4*)(e1_dst + (long)t * E))[q];
    int dd[4] = {d4.x, d4.y, d4.z, d4.w};
#pragma unroll
    for (int c = 0; c < 4; ++c) {
        int d = dd[c];
        if (!((bm[d >> 5] >> (d & 31)) & 1u)) continue;
        long j = q * 4 + c;
        int src = e1_src[(long)t * E + j];
        int ns = min(cnt2[t], MAXS);
        for (int i = 0; i < ns; ++i) {
            if (items[t * MAXS + i] == d) {
                int pos = atomicAdd(&cnt1[t * MAXS + i], 1);
                if (pos < CAP1) list1[((long)t * MAXS + i) * CAP1 + pos] = src;
            }
        }
    }
}

// K3: per slot, gather its e1 srcs, mean, then
// h_item = relu(mean @ W1a_l.T + b1a_l + x_item @ W1a_r.T); sum into hsum.
__global__ void k_hitem(const float* __restrict__ x_item, const float* __restrict__ x_inf,
                        const float* __restrict__ W1a_l, const float* __restrict__ b1a_l,
                        const float* __restrict__ W1a_r,
                        const int* __restrict__ cnt2, const int* __restrict__ items,
                        const int* __restrict__ cnt1, const int* __restrict__ list1,
                        float* __restrict__ hsum) {
    int t = blockIdx.y, slot = blockIdx.x;
    int ns = min(cnt2[t], MAXS);
    if (slot >= ns) return;
    __shared__ float z1[F], xk[F];
    int item = items[t * MAXS + slot];
    int ne = cnt1[t * MAXS + slot];
    float inv = 1.0f / fmaxf((float)ne, 1.0f);
    int nr = min(ne, CAP1);
    if (threadIdx.x < F) {
        int f = threadIdx.x;
        const int* lst = list1 + ((long)t * MAXS + slot) * CAP1;
        float s = 0.0f;
        for (int e = 0; e < nr; ++e)
            s += x_inf[((long)t * NI + lst[e]) * F + f];
        z1[f] = s * inv;
        xk[f] = x_item[((long)t * NK + item) * F + f];
    }
    __syncthreads();
    int h = threadIdx.x;  // 256 == H
    float acc = b1a_l[h];
    const float* wl = W1a_l + h * F;
    const float* wr = W1a_r + h * F;
    for (int f = 0; f < F; ++f) acc += z1[f] * wl[f] + xk[f] * wr[f];
    acc = fmaxf(acc, 0.0f);
    atomicAdd(&hsum[t * H + h], acc);
}

// K4: fused tail. Block b first computes o[t=b] and gi[t=b] (layer2 + W_ih
// matvec), then a grid barrier, then the persistent 8-block GRU. Block 0
// runs attention + prediction head after the last step.
__global__ void __launch_bounds__(256, 1)
k_gru(const float* __restrict__ x_inf, const float* __restrict__ x_item,
      const int* __restrict__ target_p,
      const float* __restrict__ W1b_l, const float* __restrict__ b1b_l,
      const float* __restrict__ W1b_r,
      const float* __restrict__ W2b_l, const float* __restrict__ b2b_l,
      const float* __restrict__ W2b_r,
      const int* __restrict__ cnt2, const int* __restrict__ items,
      const float* __restrict__ hsum,
      const float* __restrict__ W_ih, const float* __restrict__ b_ih,
      const float* __restrict__ W_hh, const float* __restrict__ b_hh,
      const float* __restrict__ W_att, const float* __restrict__ b_att,
      const float* __restrict__ W_p1, const float* __restrict__ b_p1,
      const float* __restrict__ W_p2, const float* __restrict__ b_p2,
      float* __restrict__ gi, float* __restrict__ rnn,
      int* __restrict__ bar, float* __restrict__ out) {
    __shared__ float w[3 * RPB][H];   // 96 KiB
    __shared__ float h[H];
    __shared__ float srnn[T][H];      // 8 KiB (block 0 tail)
    __shared__ float satt[T], tmp[H], hid[128];
    __shared__ float z2[F], xt[F], hinf[H], mh[H], so[O];
    int b = blockIdx.x, tid = threadIdx.x;
    int wv = tid >> 6, lane = tid & 63;

    // ---- tail phase: o[t=b] and gi[t=b] ----
    {
        int t = b;
        int target = *target_p;
        int ns = min(cnt2[t], MAXS);
        float c2 = fmaxf((float)cnt2[t], 1.0f);
        if (tid < F) {
            int f = tid;
            float s = 0.0f;
            for (int i = 0; i < ns; ++i)
                s += x_item[((long)t * NK + items[t * MAXS + i]) * F + f];
            z2[f] = s / c2;
            xt[f] = x_inf[((long)t * NI + target) * F + f];
        }
        __syncthreads();
        {
            float acc = b1b_l[tid];
            const float* wl = W1b_l + tid * F;
            const float* wr = W1b_r + tid * F;
            for (int f = 0; f < F; ++f) acc += z2[f] * wl[f] + xt[f] * wr[f];
            hinf[tid] = fmaxf(acc, 0.0f);
            mh[tid] = hsum[t * H + tid] / c2;
        }
        __syncthreads();
        if (tid < O) {
            float acc = b2b_l[tid];
            const float* wl = W2b_l + tid * H;
            const float* wr = W2b_r + tid * H;
            for (int k = 0; k < H; ++k) acc += mh[k] * wl[k] + hinf[k] * wr[k];
            so[tid] = acc;
        }
        __syncthreads();
        // gi rows (same per-row arithmetic/reduction order as the old k_gi)
        for (int row = wv; row < G3; row += 4) {
            const float* wih = W_ih + (long)row * O;
            float s = wih[lane] * so[lane] + wih[lane + 64] * so[lane + 64];
            for (int off = 32; off; off >>= 1) s += __shfl_down(s, off);
            if (lane == 0)
                __hip_atomic_store(&gi[t * G3 + row], s + b_ih[row],
                                   __ATOMIC_RELAXED, __HIP_MEMORY_SCOPE_AGENT);
        }
    }
    __syncthreads();
    if (tid == 0) {
        __threadfence();
        __hip_atomic_fetch_add(&bar[8], 1, __ATOMIC_RELEASE, __HIP_MEMORY_SCOPE_AGENT);
    }
    // load W_hh slice (overlaps other blocks' tail phases)
    for (int idx = tid; idx < 3 * RPB * H; idx += 256) {
        int r = idx >> 8, k = idx & 255;
        int g = r / RPB, j = r - g * RPB;
        w[r][k] = W_hh[((long)(g * H + b * RPB + j)) * H + k];
    }
    h[tid] = 0.0f;
    if (tid == 0) {
        while (__hip_atomic_load(&bar[8], __ATOMIC_ACQUIRE, __HIP_MEMORY_SCOPE_AGENT) < NB)
            __builtin_amdgcn_s_sleep(1);
        __threadfence();
    }
    __syncthreads();

    // ---- GRU recurrence ----
    for (int t = 0; t < T; ++t) {
        for (int j = wv; j < RPB; j += 4) {
            float sr = 0.f, sz = 0.f, sn = 0.f;
            for (int c = 0; c < 4; ++c) {
                int k = lane + 64 * c;
                float hk = h[k];
                sr += w[j][k] * hk;
                sz += w[RPB + j][k] * hk;
                sn += w[2 * RPB + j][k] * hk;
            }
            for (int off = 32; off; off >>= 1) {
                sr += __shfl_down(sr, off);
                sz += __shfl_down(sz, off);
                sn += __shfl_down(sn, off);
            }
            if (lane == 0) {
                int i = b * RPB + j;
                float gir = __hip_atomic_load(&gi[t * G3 + i], __ATOMIC_RELAXED,
                                              __HIP_MEMORY_SCOPE_AGENT);
                float giz = __hip_atomic_load(&gi[t * G3 + H + i], __ATOMIC_RELAXED,
                                              __HIP_MEMORY_SCOPE_AGENT);
                float gin = __hip_atomic_load(&gi[t * G3 + 2 * H + i], __ATOMIC_RELAXED,
                                              __HIP_MEMORY_SCOPE_AGENT);
                float r = 1.0f / (1.0f + expf(-(gir + sr + b_hh[i])));
                float z = 1.0f / (1.0f + expf(-(giz + sz + b_hh[H + i])));
                float n = tanhf(gin + r * (sn + b_hh[2 * H + i]));
                float hn = (1.0f - z) * n + z * h[i];
                __hip_atomic_store(&rnn[t * H + i], hn, __ATOMIC_RELAXED,
                                   __HIP_MEMORY_SCOPE_AGENT);
            }
        }
        __syncthreads();
        if (tid == 0) {
            __threadfence();
            __hip_atomic_fetch_add(&bar[t], 1, __ATOMIC_RELEASE, __HIP_MEMORY_SCOPE_AGENT);
            while (__hip_atomic_load(&bar[t], __ATOMIC_ACQUIRE, __HIP_MEMORY_SCOPE_AGENT) < NB)
                __builtin_amdgcn_s_sleep(1);
            __threadfence();
        }
        __syncthreads();
        h[tid] = __hip_atomic_load(&rnn[t * H + tid], __ATOMIC_RELAXED,
                                   __HIP_MEMORY_SCOPE_AGENT);
        __syncthreads();
    }
    if (b != 0) return;
    // ---- attention + head (block 0) ----
    for (int idx = tid; idx < T * H; idx += 256)
        srnn[idx >> 8][idx & 255] = __hip_atomic_load(&rnn[idx], __ATOMIC_RELAXED,
                                                      __HIP_MEMORY_SCOPE_AGENT);
    __syncthreads();
    {   // att scores: 32 lanes per t
        int tt = tid >> 5, l32 = tid & 31;
        float a = 0.f;
        for (int c = 0; c < 8; ++c) {
            int k = l32 + 32 * c;
            a += W_att[k] * srnn[tt][k];
        }
        for (int off = 16; off; off >>= 1) a += __shfl_down(a, off, 32);
        if (l32 == 0) satt[tt] = a + b_att[0];
    }
    __syncthreads();
    if (tid == 0) {
        float m = satt[0];
        for (int t = 1; t < T; ++t) m = fmaxf(m, satt[t]);
        float s = 0.f;
        for (int t = 0; t < T; ++t) { satt[t] = expf(satt[t] - m); s += satt[t]; }
        for (int t = 0; t < T; ++t) satt[t] /= s;
    }
    __syncthreads();
    {
        float ctx = 0.f;
        for (int t = 0; t < T; ++t) ctx += satt[t] * srnn[t][tid];
        tmp[tid] = ctx;
    }
    __syncthreads();
    if (tid < 128) {
        float a = b_p1[tid];
        const float* wp = W_p1 + (long)tid * H;
        for (int k = 0; k < H; ++k) a += wp[k] * tmp[k];
        hid[tid] = fmaxf(a, 0.0f);
    }
    __syncthreads();
    if (tid == 0) {
        float s = b_p2[0];
        for (int k = 0; k < 128; ++k) s += W_p2[k] * hid[k];
        out[0] = s;
    }
}

extern "C" void kernel_launch(void* const* d_in, const int* in_sizes, int n_in,
                              void* d_out, int out_size, void* d_ws, size_t ws_size,
                              hipStream_t stream) {
    const float* x_inf  = (const float*)d_in[0];
    const float* x_item = (const float*)d_in[1];
    const int* e1_src = (const int*)d_in[2];
    const int* e1_dst = (const int*)d_in[3];
    const int* e2_src = (const int*)d_in[4];
    const int* e2_dst = (const int*)d_in[5];
    const int* target_p = (const int*)d_in[6];
    const float* W1a_l = (const float*)d_in[7];
    const float* b1a_l = (const float*)d_in[8];
    const float* W1a_r = (const float*)d_in[9];
    const float* W1b_l = (const float*)d_in[10];
    const float* b1b_l = (const float*)d_in[11];
    const float* W1b_r = (const float*)d_in[12];
    const float* W2b_l = (const float*)d_in[16];
    const float* b2b_l = (const float*)d_in[17];
    const float* W2b_r = (const float*)d_in[18];
    const float* W_ih = (const float*)d_in[19];
    const float* W_hh = (const float*)d_in[20];
    const float* b_ih = (const float*)d_in[21];
    const float* b_hh = (const float*)d_in[22];
    const float* W_att = (const float*)d_in[23];
    const float* b_att = (const float*)d_in[24];
    const float* W_p1 = (const float*)d_in[25];
    const float* b_p1 = (const float*)d_in[26];
    const float* W_p2 = (const float*)d_in[27];
    const float* b_p2 = (const float*)d_in[28];
    float* out = (float*)d_out;

    char* ws = (char*)d_ws;
    int*      cnt2  = (int*)(ws + OFF_CNT2);
    int*      items = (int*)(ws + OFF_ITEMS);
    int*      cnt1  = (int*)(ws + OFF_CNT1);
    float*    hsum  = (float*)(ws + OFF_HSUM);
    int*      bar   = (int*)(ws + OFF_BAR);
    unsigned* gbm   = (unsigned*)(ws + OFF_GBM);
    int*      list1 = (int*)(ws + OFF_LIST1);
    float*    gi    = (float*)(ws + OFF_GI);
    float*    rnn   = (float*)(ws + OFF_RNN);

    hipMemsetAsync(d_ws, 0, WS_ZERO, stream);

    dim3 g1((EQ + 255) / 256, T);
    k_find_e2<<<g1, 256, 0, stream>>>(e2_src, e2_dst, target_p, cnt2, items, gbm);

    k_scan_e1<<<g1, 256, 0, stream>>>(e1_src, e1_dst, cnt2, items, gbm, cnt1, list1);

    dim3 g3(MAXS, T);
    k_hitem<<<g3, 256, 0, stream>>>(x_item, x_inf, W1a_l, b1a_l, W1a_r,
                                    cnt2, items, cnt1, list1, hsum);

    k_gru<<<NB, 256, 0, stream>>>(x_inf, x_item, target_p,
                                  W1b_l, b1b_l, W1b_r, W2b_l, b2b_l, W2b_r,
                                  cnt2, items, hsum, W_ih, b_ih, W_hh, b_hh,
                                  W_att, b_att, W_p1, b_p1, W_p2, b_p2,
                                  gi, rnn, bar, out);
}

// Round 2
// 669.337 us; speedup vs baseline: 1.0456x; 1.0456x over previous
//
#include <hip/hip_runtime.h>
#include <math.h>

#define T 8
#define NI 20000
#define NK 50000
#define F 128
#define H 256
#define O 128
#define E 500000
#define G3 (3*H)          // 768
#define MAXS 256          // slot cap per timestep (E[slots]=25)
#define CAP1 256          // per-slot e1 edge cap (E[edges/slot]=10)
#define BMW 1568          // ceil(NK/32)
#define NB 8              // persistent GRU blocks
#define RPB 32            // h-indices per GRU block (H/NB)
#define GROWS (G3/NB)     // 96 gi rows per block
#define EQ (E/4)          // int4 quads per timestep

// ---------------- workspace layout (bytes) ----------------
// zeroed prefix:
#define OFF_CNT2   0                        // T ints
#define OFF_ITEMS  32                       // T*MAXS ints
#define OFF_CNT1   (32 + T*MAXS*4)          // T*MAXS ints
#define OFF_HSUM   (OFF_CNT1 + T*MAXS*4)    // T*H floats
#define OFF_BAR    (OFF_HSUM + T*H*4)       // 16 ints
#define OFF_GBM    (OFF_BAR + 64)           // T*BMW uints
#define WS_ZERO    (OFF_GBM + T*BMW*4)      // ~73 KB memset
// not zeroed (fully written before read):
#define OFF_LIST1  WS_ZERO                  // T*MAXS*CAP1 ints (2 MB)
#define OFF_GI     (OFF_LIST1 + (size_t)T*MAXS*CAP1*4)  // T*G3 floats
#define OFF_RNN    (OFF_GI + T*G3*4)        // T*H floats
#define OFF_O      (OFF_RNN + T*H*4)        // T*O floats
#define WS_USED    (OFF_O + T*O*4)

// K1: scan e2_dst (int4) for edges into target; record src items (slots),
// set global item bitmap.
__global__ void k_find_e2(const int* __restrict__ e2_src, const int* __restrict__ e2_dst,
                          const int* __restrict__ target_p,
                          int* __restrict__ cnt2, int* __restrict__ items,
                          unsigned* __restrict__ gbm) {
    int t = blockIdx.y;
    long q = (long)blockIdx.x * 256 + threadIdx.x;
    if (q >= EQ) return;
    int target = *target_p;
    const int4 d4 = ((const int4*)(e2_dst + (long)t * E))[q];
    int dd[4] = {d4.x, d4.y, d4.z, d4.w};
#pragma unroll
    for (int c = 0; c < 4; ++c) {
        if (dd[c] == target) {
            long j = q * 4 + c;
            int src = e2_src[(long)t * E + j];
            int pos = atomicAdd(&cnt2[t], 1);
            if (pos < MAXS) {
                items[t * MAXS + pos] = src;
                atomicOr(&gbm[t * BMW + (src >> 5)], 1u << (src & 31));
            }
        }
    }
}

// K2: scan e1_dst (int4) against global bitmap; matching edges append their
// src index into the slot's list.
__global__ void k_scan_e1(const int* __restrict__ e1_src, const int* __restrict__ e1_dst,
                          const int* __restrict__ cnt2, const int* __restrict__ items,
                          const unsigned* __restrict__ gbm,
                          int* __restrict__ cnt1, int* __restrict__ list1) {
    int t = blockIdx.y;
    long q = (long)blockIdx.x * 256 + threadIdx.x;
    if (q >= EQ) return;
    const unsigned* bm = gbm + t * BMW;
    const int4 d4 = ((const int4*)(e1_dst + (long)t * E))[q];
    int dd[4] = {d4.x, d4.y, d4.z, d4.w};
#pragma unroll
    for (int c = 0; c < 4; ++c) {
        int d = dd[c];
        if (!((bm[d >> 5] >> (d & 31)) & 1u)) continue;
        long j = q * 4 + c;
        int src = e1_src[(long)t * E + j];
        int ns = min(cnt2[t], MAXS);
        for (int i = 0; i < ns; ++i) {
            if (items[t * MAXS + i] == d) {
                int pos = atomicAdd(&cnt1[t * MAXS + i], 1);
                if (pos < CAP1) list1[((long)t * MAXS + i) * CAP1 + pos] = src;
            }
        }
    }
}

// K3: per slot, gather its e1 srcs, mean, then
// h_item = relu(mean @ W1a_l.T + b1a_l + x_item @ W1a_r.T); sum into hsum.
__global__ void k_hitem(const float* __restrict__ x_item, const float* __restrict__ x_inf,
                        const float* __restrict__ W1a_l, const float* __restrict__ b1a_l,
                        const float* __restrict__ W1a_r,
                        const int* __restrict__ cnt2, const int* __restrict__ items,
                        const int* __restrict__ cnt1, const int* __restrict__ list1,
                        float* __restrict__ hsum) {
    int t = blockIdx.y, slot = blockIdx.x;
    int ns = min(cnt2[t], MAXS);
    if (slot >= ns) return;
    __shared__ float z1[F], xk[F];
    int item = items[t * MAXS + slot];
    int ne = cnt1[t * MAXS + slot];
    float inv = 1.0f / fmaxf((float)ne, 1.0f);
    int nr = min(ne, CAP1);
    if (threadIdx.x < F) {
        int f = threadIdx.x;
        const int* lst = list1 + ((long)t * MAXS + slot) * CAP1;
        float s = 0.0f;
        for (int e = 0; e < nr; ++e)
            s += x_inf[((long)t * NI + lst[e]) * F + f];
        z1[f] = s * inv;
        xk[f] = x_item[((long)t * NK + item) * F + f];
    }
    __syncthreads();
    int h = threadIdx.x;  // 256 == H
    float acc = b1a_l[h];
    const float* wl = W1a_l + h * F;
    const float* wr = W1a_r + h * F;
    for (int f = 0; f < F; ++f) acc += z1[f] * wl[f] + xk[f] * wr[f];
    acc = fmaxf(acc, 0.0f);
    atomicAdd(&hsum[t * H + h], acc);
}

// K4: fused tail. Phase 1: block b computes o[t=b] (layer2, wave-per-row).
// Barrier. Phase 2: block b computes gi ROWS [96b,96b+96) for ALL t (reads a
// 49KB W_ih slice once). Barrier. Recurrence reads gi from LDS (no atomics
// in the loop); h exchanged via the previously-verified rnn pattern.
// Block 0 runs attention + head at the end.
__global__ void __launch_bounds__(256, 1)
k_gru(const float* __restrict__ x_inf, const float* __restrict__ x_item,
      const int* __restrict__ target_p,
      const float* __restrict__ W1b_l, const float* __restrict__ b1b_l,
      const float* __restrict__ W1b_r,
      const float* __restrict__ W2b_l, const float* __restrict__ b2b_l,
      const float* __restrict__ W2b_r,
      const int* __restrict__ cnt2, const int* __restrict__ items,
      const float* __restrict__ hsum,
      const float* __restrict__ W_ih, const float* __restrict__ b_ih,
      const float* __restrict__ W_hh, const float* __restrict__ b_hh,
      const float* __restrict__ W_att, const float* __restrict__ b_att,
      const float* __restrict__ W_p1, const float* __restrict__ b_p1,
      const float* __restrict__ W_p2, const float* __restrict__ b_p2,
      float* __restrict__ gi, float* __restrict__ rnn, float* __restrict__ o_ws,
      int* __restrict__ bar, float* __restrict__ out) {
    __shared__ float w[3 * RPB][H];   // 96 KiB
    __shared__ float h[H];
    __shared__ float srnn[T][H];      // 8 KiB (block 0 tail)
    __shared__ float satt[T], tmp[H], hid[128];
    __shared__ float z2[F], xt[F], hinf[H], mh[H];
    __shared__ float so_all[T][O];    // 4 KiB
    __shared__ float sgi[T][3][RPB];  // 3 KiB
    int b = blockIdx.x, tid = threadIdx.x;
    int wv = tid >> 6, lane = tid & 63;

    // ---- phase 1: o[t=b] ----
    {
        int t = b;
        int target = *target_p;
        int ns = min(cnt2[t], MAXS);
        float c2 = fmaxf((float)cnt2[t], 1.0f);
        if (tid < F) {
            int f = tid;
            float s = 0.0f;
            for (int i = 0; i < ns; ++i)
                s += x_item[((long)t * NK + items[t * MAXS + i]) * F + f];
            z2[f] = s / c2;
            xt[f] = x_inf[((long)t * NI + target) * F + f];
        }
        mh[tid] = hsum[t * H + tid] / c2;
        __syncthreads();
        // hinf rows, wave-per-row (coalesced weight reads)
        for (int r = wv; r < H; r += 4) {
            float wl0 = W1b_l[r * F + lane],      wl1 = W1b_l[r * F + 64 + lane];
            float wr0 = W1b_r[r * F + lane],      wr1 = W1b_r[r * F + 64 + lane];
            float s = wl0 * z2[lane] + wl1 * z2[lane + 64]
                    + wr0 * xt[lane] + wr1 * xt[lane + 64];
            for (int off = 32; off; off >>= 1) s += __shfl_down(s, off);
            if (lane == 0) hinf[r] = fmaxf(s + b1b_l[r], 0.0f);
        }
        __syncthreads();
        // o rows, wave-per-row
        for (int r = wv; r < O; r += 4) {
            float s = 0.0f;
            for (int c = 0; c < 4; ++c) {
                int k = lane + 64 * c;
                s += W2b_l[r * H + k] * mh[k] + W2b_r[r * H + k] * hinf[k];
            }
            for (int off = 32; off; off >>= 1) s += __shfl_down(s, off);
            if (lane == 0)
                __hip_atomic_store(&o_ws[t * O + r], s + b2b_l[r],
                                   __ATOMIC_RELAXED, __HIP_MEMORY_SCOPE_AGENT);
        }
    }
    __syncthreads();
    if (tid == 0) {
        __threadfence();
        __hip_atomic_fetch_add(&bar[8], 1, __ATOMIC_RELEASE, __HIP_MEMORY_SCOPE_AGENT);
        while (__hip_atomic_load(&bar[8], __ATOMIC_ACQUIRE, __HIP_MEMORY_SCOPE_AGENT) < NB)
            __builtin_amdgcn_s_sleep(1);
        __threadfence();
    }
    __syncthreads();
    // bulk-load all o vectors (coalesced agent loads)
    for (int idx = tid; idx < T * O; idx += 256)
        so_all[idx >> 7][idx & 127] = __hip_atomic_load(&o_ws[idx], __ATOMIC_RELAXED,
                                                        __HIP_MEMORY_SCOPE_AGENT);
    __syncthreads();
    // ---- phase 2: gi rows [96b, 96b+96) for all t ----
    for (int lr = wv; lr < GROWS; lr += 4) {
        int r = b * GROWS + lr;
        float w0 = W_ih[(long)r * O + lane];
        float w1 = W_ih[(long)r * O + 64 + lane];
        float bi = b_ih[r];
#pragma unroll
        for (int t = 0; t < T; ++t) {
            float s = w0 * so_all[t][lane] + w1 * so_all[t][lane + 64];
            for (int off = 32; off; off >>= 1) s += __shfl_down(s, off);
            if (lane == 0)
                __hip_atomic_store(&gi[t * G3 + r], s + bi,
                                   __ATOMIC_RELAXED, __HIP_MEMORY_SCOPE_AGENT);
        }
    }
    __syncthreads();
    if (tid == 0) {
        __threadfence();
        __hip_atomic_fetch_add(&bar[9], 1, __ATOMIC_RELEASE, __HIP_MEMORY_SCOPE_AGENT);
    }
    // load W_hh slice (overlaps other blocks' phase 2)
    for (int idx = tid; idx < 3 * RPB * H; idx += 256) {
        int r = idx >> 8, k = idx & 255;
        int g = r / RPB, j = r - g * RPB;
        w[r][k] = W_hh[((long)(g * H + b * RPB + j)) * H + k];
    }
    h[tid] = 0.0f;
    if (tid == 0) {
        while (__hip_atomic_load(&bar[9], __ATOMIC_ACQUIRE, __HIP_MEMORY_SCOPE_AGENT) < NB)
            __builtin_amdgcn_s_sleep(1);
        __threadfence();
    }
    __syncthreads();
    // bulk-load this block's gi slice into LDS: sgi[t][g][j] = gi[t*G3+g*H+b*32+j]
    for (int idx = tid; idx < T * 3 * RPB; idx += 256) {
        int t = idx / 96, rem = idx - t * 96;
        int g = rem >> 5, j = rem & 31;
        sgi[t][g][j] = __hip_atomic_load(&gi[t * G3 + g * H + b * RPB + j],
                                         __ATOMIC_RELAXED, __HIP_MEMORY_SCOPE_AGENT);
    }
    __syncthreads();

    // ---- GRU recurrence (no atomics except h exchange) ----
    for (int t = 0; t < T; ++t) {
        for (int j = wv; j < RPB; j += 4) {
            float sr = 0.f, sz = 0.f, sn = 0.f;
            for (int c = 0; c < 4; ++c) {
                int k = lane + 64 * c;
                float hk = h[k];
                sr += w[j][k] * hk;
                sz += w[RPB + j][k] * hk;
                sn += w[2 * RPB + j][k] * hk;
            }
            for (int off = 32; off; off >>= 1) {
                sr += __shfl_down(sr, off);
                sz += __shfl_down(sz, off);
                sn += __shfl_down(sn, off);
            }
            if (lane == 0) {
                int i = b * RPB + j;
                float r = 1.0f / (1.0f + expf(-(sgi[t][0][j] + sr + b_hh[i])));
                float z = 1.0f / (1.0f + expf(-(sgi[t][1][j] + sz + b_hh[H + i])));
                float n = tanhf(sgi[t][2][j] + r * (sn + b_hh[2 * H + i]));
                float hn = (1.0f - z) * n + z * h[i];
                __hip_atomic_store(&rnn[t * H + i], hn, __ATOMIC_RELAXED,
                                   __HIP_MEMORY_SCOPE_AGENT);
            }
        }
        __syncthreads();
        if (tid == 0) {
            __threadfence();
            __hip_atomic_fetch_add(&bar[t], 1, __ATOMIC_RELEASE, __HIP_MEMORY_SCOPE_AGENT);
            while (__hip_atomic_load(&bar[t], __ATOMIC_ACQUIRE, __HIP_MEMORY_SCOPE_AGENT) < NB)
                __builtin_amdgcn_s_sleep(1);
            __threadfence();
        }
        __syncthreads();
        h[tid] = __hip_atomic_load(&rnn[t * H + tid], __ATOMIC_RELAXED,
                                   __HIP_MEMORY_SCOPE_AGENT);
        __syncthreads();
    }
    if (b != 0) return;
    // ---- attention + head (block 0) ----
    for (int idx = tid; idx < T * H; idx += 256)
        srnn[idx >> 8][idx & 255] = __hip_atomic_load(&rnn[idx], __ATOMIC_RELAXED,
                                                      __HIP_MEMORY_SCOPE_AGENT);
    __syncthreads();
    {   // att scores: 32 lanes per t
        int tt = tid >> 5, l32 = tid & 31;
        float a = 0.f;
        for (int c = 0; c < 8; ++c) {
            int k = l32 + 32 * c;
            a += W_att[k] * srnn[tt][k];
        }
        for (int off = 16; off; off >>= 1) a += __shfl_down(a, off, 32);
        if (l32 == 0) satt[tt] = a + b_att[0];
    }
    __syncthreads();
    if (tid == 0) {
        float m = satt[0];
        for (int t = 1; t < T; ++t) m = fmaxf(m, satt[t]);
        float s = 0.f;
        for (int t = 0; t < T; ++t) { satt[t] = expf(satt[t] - m); s += satt[t]; }
        for (int t = 0; t < T; ++t) satt[t] /= s;
    }
    __syncthreads();
    {
        float ctx = 0.f;
        for (int t = 0; t < T; ++t) ctx += satt[t] * srnn[t][tid];
        tmp[tid] = ctx;
    }
    __syncthreads();
    if (tid < 128) {
        float a = b_p1[tid];
        const float* wp = W_p1 + (long)tid * H;
        for (int k = 0; k < H; ++k) a += wp[k] * tmp[k];
        hid[tid] = fmaxf(a, 0.0f);
    }
    __syncthreads();
    if (tid == 0) {
        float s = b_p2[0];
        for (int k = 0; k < 128; ++k) s += W_p2[k] * hid[k];
        out[0] = s;
    }
}

extern "C" void kernel_launch(void* const* d_in, const int* in_sizes, int n_in,
                              void* d_out, int out_size, void* d_ws, size_t ws_size,
                              hipStream_t stream) {
    const float* x_inf  = (const float*)d_in[0];
    const float* x_item = (const float*)d_in[1];
    const int* e1_src = (const int*)d_in[2];
    const int* e1_dst = (const int*)d_in[3];
    const int* e2_src = (const int*)d_in[4];
    const int* e2_dst = (const int*)d_in[5];
    const int* target_p = (const int*)d_in[6];
    const float* W1a_l = (const float*)d_in[7];
    const float* b1a_l = (const float*)d_in[8];
    const float* W1a_r = (const float*)d_in[9];
    const float* W1b_l = (const float*)d_in[10];
    const float* b1b_l = (const float*)d_in[11];
    const float* W1b_r = (const float*)d_in[12];
    const float* W2b_l = (const float*)d_in[16];
    const float* b2b_l = (const float*)d_in[17];
    const float* W2b_r = (const float*)d_in[18];
    const float* W_ih = (const float*)d_in[19];
    const float* W_hh = (const float*)d_in[20];
    const float* b_ih = (const float*)d_in[21];
    const float* b_hh = (const float*)d_in[22];
    const float* W_att = (const float*)d_in[23];
    const float* b_att = (const float*)d_in[24];
    const float* W_p1 = (const float*)d_in[25];
    const float* b_p1 = (const float*)d_in[26];
    const float* W_p2 = (const float*)d_in[27];
    const float* b_p2 = (const float*)d_in[28];
    float* out = (float*)d_out;

    char* ws = (char*)d_ws;
    int*      cnt2  = (int*)(ws + OFF_CNT2);
    int*      items = (int*)(ws + OFF_ITEMS);
    int*      cnt1  = (int*)(ws + OFF_CNT1);
    float*    hsum  = (float*)(ws + OFF_HSUM);
    int*      bar   = (int*)(ws + OFF_BAR);
    unsigned* gbm   = (unsigned*)(ws + OFF_GBM);
    int*      list1 = (int*)(ws + OFF_LIST1);
    float*    gi    = (float*)(ws + OFF_GI);
    float*    rnn   = (float*)(ws + OFF_RNN);
    float*    o_ws  = (float*)(ws + OFF_O);

    hipMemsetAsync(d_ws, 0, WS_ZERO, stream);

    dim3 g1((EQ + 255) / 256, T);
    k_find_e2<<<g1, 256, 0, stream>>>(e2_src, e2_dst, target_p, cnt2, items, gbm);

    k_scan_e1<<<g1, 256, 0, stream>>>(e1_src, e1_dst, cnt2, items, gbm, cnt1, list1);

    dim3 g3(MAXS, T);
    k_hitem<<<g3, 256, 0, stream>>>(x_item, x_inf, W1a_l, b1a_l, W1a_r,
                                    cnt2, items, cnt1, list1, hsum);

    k_gru<<<NB, 256, 0, stream>>>(x_inf, x_item, target_p,
                                  W1b_l, b1b_l, W1b_r, W2b_l, b2b_l, W2b_r,
                                  cnt2, items, hsum, W_ih, b_ih, W_hh, b_hh,
                                  W_att, b_att, W_p1, b_p1, W_p2, b_p2,
                                  gi, rnn, o_ws, bar, out);
}